// Round 5
// baseline (5068.423 us; speedup 1.0000x reference)
//
#include <hip/hip_runtime.h>
#include <hip/hip_bf16.h>
#include <cmath>

#define HID 512
#define TSTEPS 784
#define BATCH 256
#define NCLS 10
#define NBLK 128
#define GRP 16      // blocks per batch-group (col slices)
#define NGRP 8      // batch groups (32 rows each)

typedef __bf16 bf16x8 __attribute__((ext_vector_type(8)));
typedef __bf16 bf16x2 __attribute__((ext_vector_type(2)));
typedef float f32x4 __attribute__((ext_vector_type(4)));
typedef float f32x2 __attribute__((ext_vector_type(2)));
typedef int   i32x4 __attribute__((ext_vector_type(4)));

#define SWS(r) (((unsigned)(r) & 7u) << 4)

// zero h0+h1 (512KB), zero flags, transpose x -> xT[784][256]
__global__ void init_all(const float* __restrict__ x, float* __restrict__ xT,
                         uint4* __restrict__ hz, unsigned* __restrict__ flg) {
    int t = blockIdx.x, tid = threadIdx.x;
    xT[t * BATCH + tid] = x[tid * TSTEPS + t];
    int i = t * 256 + tid;
    if (i < (512 << 10) / 16) hz[i] = make_uint4(0u, 0u, 0u, 0u);
    if (i < NGRP * 64) flg[i] = 0u;
}

__device__ __forceinline__ float sigmoid_f(float v) {
    return __fdividef(1.f, 1.f + __expf(-v));
}
__device__ __forceinline__ float tanh_f(float v) {
    float e = __expf(fminf(fmaxf(2.f * v, -30.f), 30.f));
    return __fdividef(e - 1.f, e + 1.f);
}

// 16B / 4B LLC-coherent ops (bypass L1+L2; LLC is the coherence point)
#define LOADX4_CC(dst, addr) \
    asm volatile("global_load_dwordx4 %0, %1, off sc0 sc1" : "=v"(dst) : "v"(addr) : "memory")
#define LOADDW_CC(dst, addr) \
    asm volatile("global_load_dword %0, %1, off sc0 sc1\n\ts_waitcnt vmcnt(0)" \
                 : "=v"(dst) : "v"(addr) : "memory")
#define STOREDW_CC(addr, val) \
    asm volatile("global_store_dword %0, %1, off sc0 sc1" :: "v"(addr), "v"(val) : "memory")

// Persistent LSTM: 128 blocks = 8 batch-groups(32 rows) x 16 col-slices(32 cols).
// W slice (128 rows x 512) in LDS for all steps; c in registers; h exchanged
// through LLC; per-group flag-array barrier (no RMW).
__global__ __launch_bounds__(512)
void lstm_persist(const float* __restrict__ xT,     // [784][256]
                  const float* __restrict__ W_hh,   // [2048][512] fp32
                  const float* __restrict__ w_in,   // [2048]
                  const float* __restrict__ b_ih,
                  const float* __restrict__ b_hh,
                  __bf16* __restrict__ h0,          // [256][512] bf16
                  __bf16* __restrict__ h1,
                  float* __restrict__ hf,           // [256][512] fp32
                  unsigned* __restrict__ flg)
{
    __shared__ __align__(16) __bf16 wlds[128 * HID];  // 128 KB, XOR-swizzled
    __shared__ float gl[4][32][34];                   // gate exchange, padded

    const int tid  = threadIdx.x;
    const int lane = tid & 63;
    const int w    = tid >> 6;           // wave 0..7
    const int s    = w & 3;              // gate (i,f,g,o)
    const int rh   = w >> 2;             // row half (0: rows 0-15, 1: 16-31)
    const int bg   = blockIdx.x >> 4;    // batch group (8)
    const int cs   = blockIdx.x & 15;    // col slice (16)
    const int b0   = bg * 32;
    const int j0   = cs * 32;
    const int rlo  = lane & 15;
    const int khi  = (lane >> 4) * 8;    // elements

    unsigned* flags = flg + bg * 64;     // 256B-separated per-group flag line

    // ---- stage W slice (128 rows x 512) into LDS once (fp32->bf16, swizzled) ----
    {
        int r = tid >> 2;                // local row 0..127
        int q = tid & 3;
        int gs = r >> 5, jj = r & 31;
        const float* src = W_hh + (size_t)(gs * HID + j0 + jj) * HID + q * 128;
        char* wbp = (char*)wlds;
        unsigned rowb = (unsigned)r * (HID * 2);
        unsigned sw   = (unsigned)(r & 7) << 4;
        #pragma unroll
        for (int cc = 0; cc < 128; cc += 8) {
            float4 va = *(const float4*)(src + cc);
            float4 vb = *(const float4*)(src + cc + 4);
            bf16x8 pk;
            pk[0]=(__bf16)va.x; pk[1]=(__bf16)va.y; pk[2]=(__bf16)va.z; pk[3]=(__bf16)va.w;
            pk[4]=(__bf16)vb.x; pk[5]=(__bf16)vb.y; pk[6]=(__bf16)vb.z; pk[7]=(__bf16)vb.w;
            *(bf16x8*)(wbp + ((rowb + (unsigned)(q * 128 + cc) * 2) ^ sw)) = pk;
        }
    }

    // per-thread cell mapping: row R (0..31), cols c0,c0+1 (of 32)
    const int R  = tid >> 4;
    const int c0 = (tid & 15) * 2;
    float win_r[4][2], bias_r[4][2];
    #pragma unroll
    for (int g = 0; g < 4; ++g)
        #pragma unroll
        for (int ii = 0; ii < 2; ++ii) {
            int idx = g * HID + j0 + c0 + ii;
            win_r[g][ii]  = w_in[idx];
            bias_r[g][ii] = b_ih[idx] + b_hh[idx];
        }
    float creg[2] = {0.f, 0.f};

    // B-fragment bases: local W rows s*32 + {0,16} + rlo
    const unsigned rB0b = (unsigned)(s * 32 +  0 + rlo) * (HID * 2);
    const unsigned rB1b = (unsigned)(s * 32 + 16 + rlo) * (HID * 2);
    const unsigned swB  = SWS(rlo);
    const char* wbp = (const char*)wlds;

    __syncthreads();

    for (int t = 0; t < TSTEPS; ++t) {
        const __bf16* hprev = (t & 1) ? h1 : h0;
        __bf16* hnext       = (t & 1) ? h0 : h1;

        float xv = xT[t * BATCH + b0 + R];   // block-independent; off critical path

        // ---- A-fragments: 16 k-steps batched from LLC into registers ----
        const __bf16* ap = hprev + (size_t)(b0 + rh * 16 + rlo) * HID + khi;
        i32x4 af[16];
        #pragma unroll
        for (int ks = 0; ks < 16; ++ks)
            LOADX4_CC(af[ks], ap + ks * 32);
        asm volatile("s_waitcnt vmcnt(0)" ::: "memory");
        __builtin_amdgcn_sched_barrier(0);

        // ---- gates: 16 rows x 32 cols for gate s, row-half rh ----
        f32x4 acc0 = {0.f,0.f,0.f,0.f}, acc1 = {0.f,0.f,0.f,0.f};
        #pragma unroll
        for (int ks = 0; ks < 16; ++ks) {
            unsigned colb = (unsigned)(khi * 2 + ks * 64);
            bf16x8 b0f = *(const bf16x8*)(wbp + ((rB0b + colb) ^ swB));
            bf16x8 b1f = *(const bf16x8*)(wbp + ((rB1b + colb) ^ swB));
            bf16x8 a   = *(bf16x8*)&af[ks];
            acc0 = __builtin_amdgcn_mfma_f32_16x16x32_bf16(a, b0f, acc0, 0, 0, 0);
            acc1 = __builtin_amdgcn_mfma_f32_16x16x32_bf16(a, b1f, acc1, 0, 0, 0);
        }
        #pragma unroll
        for (int rr = 0; rr < 4; ++rr) {
            int row = rh * 16 + (lane >> 4) * 4 + rr;   // D: col=lane&15, row=(lane>>4)*4+reg
            gl[s][row][rlo]      = acc0[rr];
            gl[s][row][16 + rlo] = acc1[rr];
        }
        __syncthreads();   // gl ready

        // ---- cell update (c in registers), h write-through to LLC ----
        {
            float hn2[2];
            #pragma unroll
            for (int ii = 0; ii < 2; ++ii) {
                int ccx = c0 + ii;
                float gi = gl[0][R][ccx] + xv * win_r[0][ii] + bias_r[0][ii];
                float gf = gl[1][R][ccx] + xv * win_r[1][ii] + bias_r[1][ii];
                float gg = gl[2][R][ccx] + xv * win_r[2][ii] + bias_r[2][ii];
                float go = gl[3][R][ccx] + xv * win_r[3][ii] + bias_r[3][ii];
                float cn = sigmoid_f(gf) * creg[ii] + sigmoid_f(gi) * tanh_f(gg);
                creg[ii] = cn;
                hn2[ii]  = sigmoid_f(go) * tanh_f(cn);
            }
            union { bf16x2 v; int i; } u;
            u.v = (bf16x2){(__bf16)hn2[0], (__bf16)hn2[1]};
            __bf16* dst = hnext + (size_t)(b0 + R) * HID + j0 + c0;
            STOREDW_CC(dst, u.i);
            if (t == TSTEPS - 1)
                *(f32x2*)(hf + (size_t)(b0 + R) * HID + j0 + c0) = (f32x2){hn2[0], hn2[1]};
        }

        if (t == TSTEPS - 1) break;

        // ---- per-group flag barrier (16 blocks, no RMW) ----
        asm volatile("s_waitcnt vmcnt(0)" ::: "memory");   // h stores at LLC
        __syncthreads();
        unsigned tgt = (unsigned)(t + 1);
        if (tid == 0) STOREDW_CC(flags + cs, tgt);
        if (tid < 16) {
            const unsigned* fp = flags + tid;
            unsigned f;
            do {
                __builtin_amdgcn_s_sleep(1);
                LOADDW_CC(f, fp);
            } while (__any((int)(f < tgt)));
        }
        __syncthreads();   // group advanced; safe to read hprev
    }
}

// out[b][j] = h_T[b] . W_lin[j] + b_lin[j]
__global__ void head(const float* __restrict__ hfp, const float* __restrict__ Wl,
                     const float* __restrict__ bl_, float* __restrict__ out)
{
    __shared__ float hr[HID];
    int b = blockIdx.x;
    for (int k = threadIdx.x; k < HID; k += blockDim.x) hr[k] = hfp[b * HID + k];
    __syncthreads();
    int j = threadIdx.x;
    if (j < NCLS) {
        float acc = bl_[j];
        for (int k = 0; k < HID; ++k) acc += hr[k] * Wl[j * HID + k];
        out[b * NCLS + j] = acc;
    }
}

extern "C" void kernel_launch(void* const* d_in, const int* in_sizes, int n_in,
                              void* d_out, int out_size, void* d_ws, size_t ws_size,
                              hipStream_t stream) {
    const float* inputs = (const float*)d_in[0];
    const float* W_ih   = (const float*)d_in[1];
    const float* W_hh   = (const float*)d_in[2];
    const float* b_ih   = (const float*)d_in[3];
    const float* b_hh   = (const float*)d_in[4];
    const float* W_lin  = (const float*)d_in[5];
    const float* b_lin  = (const float*)d_in[6];

    // ws: h0 256K | h1 256K | hf 512K | xT 784K | flags 2K
    const size_t OFS_H1  = 256u << 10;
    const size_t OFS_HF  = 512u << 10;
    const size_t OFS_XT  = 1024u << 10;
    const size_t OFS_FLG = OFS_XT + (size_t)TSTEPS * BATCH * 4;   // 128B-aligned
    const size_t NEEDED  = OFS_FLG + NGRP * 64 * 4;
    if (ws_size < NEEDED) return;

    char* ws = (char*)d_ws;
    __bf16* h0 = (__bf16*)ws;
    __bf16* h1 = (__bf16*)(ws + OFS_H1);
    float*  hf = (float*)(ws + OFS_HF);
    float*  xT = (float*)(ws + OFS_XT);
    unsigned* flg = (unsigned*)(ws + OFS_FLG);

    init_all<<<TSTEPS, BATCH, 0, stream>>>(inputs, xT, (uint4*)h0, flg);

    lstm_persist<<<NBLK, 512, 0, stream>>>(xT, W_hh, W_ih, b_ih, b_hh,
                                           h0, h1, hf, flg);

    head<<<BATCH, 64, 0, stream>>>(hf, W_lin, b_lin, (float*)d_out);
}